// Round 15
// baseline (117.586 us; speedup 1.0000x reference)
//
#include <hip/hip_runtime.h>
#include <hip/hip_fp16.h>
#include <stdint.h>

#define FM_BATCH 16384
#define ND 13
#define NF 26
#define FS 100000
#define FL 2600013            // 26*100000 + 13
#define FL_PAD 2600192        // 10157 * 256

// ws layout: flags [FL_PAD] bytes (2.6 MB), then Vt [FL_PAD][32] u32 (333 MB).
// Record = 128 B: u32[0..15] = 32 fp16 V values, u32[16] = fp32 w, rest pad.
// w rides in the SAME cache line as the V record -> per (b,f) the gather
// touches ONE random line instead of two.
#define N_MARK  (FM_BATCH * NF)         // 425984

// ---- Kernel 0: mark referenced features (races write the same value 1) ----
__global__ __launch_bounds__(256) void fm_mark(const int* __restrict__ sparse,
                                               unsigned char* __restrict__ flags)
{
    const int t = blockIdx.x * 256 + threadIdx.x;   // t = b*26 + f, flat over sparse
    const int f = t % NF;
    flags[ND + f * FS + sparse[t]] = 1;
    if (t < ND) flags[t] = 1;                       // dense features always present
}

// ---- Kernel 1: transpose + fp16-quantize referenced columns of V + fold w ----
// (R14 LDS-staged read form, unchanged read path; record stride now 128 B and
// w[j] appended to each flagged record.)
__global__ __launch_bounds__(256) void fm_prep(const float* __restrict__ V,
                                               const float* __restrict__ w,
                                               const unsigned char* __restrict__ flags,
                                               unsigned* __restrict__ Vt)
{
    __shared__ float stage[256][36];   // 36.9 KB; pad 36: col base 144 B (16B-aligned)
    const int j0 = blockIdx.x * 256;
    const int t = threadIdx.x;
    const int wv = t >> 6, l = t & 63;

    float va[8][4];
    if (j0 + 256 <= FL) {
#pragma unroll
        for (int p = 0; p < 8; ++p) {               // rows wv, wv+4, ..., wv+28
            const float* rp = V + (size_t)(wv + 4 * p) * FL + j0;
#pragma unroll
            for (int i = 0; i < 4; ++i)
                va[p][i] = rp[i * 64 + l];
        }
    } else {
        // tail panel (one block): per-element guard
#pragma unroll
        for (int p = 0; p < 8; ++p) {
#pragma unroll
            for (int i = 0; i < 4; ++i) {
                const int j = j0 + i * 64 + l;
                va[p][i] = (j < FL) ? V[(size_t)(wv + 4 * p) * FL + j] : 0.f;
            }
        }
    }

#pragma unroll
    for (int p = 0; p < 8; ++p)
#pragma unroll
        for (int i = 0; i < 4; ++i)
            stage[i * 64 + l][wv + 4 * p] = va[p][i];
    __syncthreads();

    const int j = j0 + t;
    if (j < FL && flags[j]) {
        unsigned pk[16];
#pragma unroll
        for (int r = 0; r < 16; ++r)
            pk[r] = (unsigned)__half_as_ushort(__float2half_rn(stage[t][2 * r])) |
                    ((unsigned)__half_as_ushort(__float2half_rn(stage[t][2 * r + 1])) << 16);
        unsigned* dst = Vt + (size_t)j * 32;
#pragma unroll
        for (int c = 0; c < 4; ++c)
            *(uint4*)(dst + 4 * c) = make_uint4(pk[4 * c], pk[4 * c + 1],
                                                pk[4 * c + 2], pk[4 * c + 3]);
        dst[16] = __float_as_uint(w[j]);            // w in the same 128 B line
    }
}

// ---- Kernel 2: the whole FM. 32 lanes/sample = 16 lanes x 2 field-halves.
// Each 16-lane group loads one uint2/lane = the full 128 B record in one
// wave instruction; lanes 0-7 decode 4 fp16 (ks 4q..4q+3), lane 8 takes w.
// 2048 blocks -> 32 waves/CU.
__global__ __launch_bounds__(256) void fm_gather(
    const float* __restrict__ dense,   // [BATCH][13]
    const int*   __restrict__ sparse,  // [BATCH][26]
    const float* __restrict__ w0,      // [1]
    const unsigned* __restrict__ Vt,   // [FL_PAD][32] u32 records
    float* __restrict__ out)           // [BATCH]
{
    const int tid = blockIdx.x * 256 + threadIdx.x;
    const int b = tid >> 5;            // sample
    const int lane32 = tid & 31;
    const int q = lane32 & 15;         // 8 B slot within the record
    const int h = lane32 >> 4;         // field half

    float2 L01 = make_float2(0.f, 0.f), L23 = make_float2(0.f, 0.f);
    float2 S01 = make_float2(0.f, 0.f), S23 = make_float2(0.f, 0.f);
    float first = 0.f;
    const float* __restrict__ db = dense + b * ND;
    const int*   __restrict__ sb = sparse + b * NF;

    if (h == 0) {
#pragma unroll
        for (int d = 0; d < ND; ++d) {
            const uint2 r = *(const uint2*)(Vt + (size_t)d * 32 + q * 2);
            const float x = db[d];
            if (q < 8) {
                const float2 v01 = __half22float2(*(const __half2*)&r.x);
                const float2 v23 = __half22float2(*(const __half2*)&r.y);
                float a;
                a = x * v01.x; L01.x += a; S01.x += a * a;
                a = x * v01.y; L01.y += a; S01.y += a * a;
                a = x * v23.x; L23.x += a; S23.x += a * a;
                a = x * v23.y; L23.y += a; S23.y += a * a;
            } else if (q == 8) {
                first += x * __uint_as_float(r.x);
            }
        }
    }

    // 13 sparse fields per half; one 128 B line per (b,f)
    const int f0 = h * 13;
#pragma unroll
    for (int ff = 0; ff < 13; ++ff) {
        const int f = f0 + ff;
        const int idx = ND + f * FS + sb[f];
        const uint2 r = *(const uint2*)(Vt + (size_t)idx * 32 + q * 2);
        if (q < 8) {
            const float2 v01 = __half22float2(*(const __half2*)&r.x);
            const float2 v23 = __half22float2(*(const __half2*)&r.y);
            L01.x += v01.x; S01.x += v01.x * v01.x;
            L01.y += v01.y; S01.y += v01.y * v01.y;
            L23.x += v23.x; S23.x += v23.x * v23.x;
            L23.y += v23.y; S23.y += v23.y * v23.y;
        } else if (q == 8) {
            first += __uint_as_float(r.x);
        }
    }

    // combine the two field-halves per k (xor 16 swaps halves)
    L01.x += __shfl_xor(L01.x, 16);  S01.x += __shfl_xor(S01.x, 16);
    L01.y += __shfl_xor(L01.y, 16);  S01.y += __shfl_xor(S01.y, 16);
    L23.x += __shfl_xor(L23.x, 16);  S23.x += __shfl_xor(S23.x, 16);
    L23.y += __shfl_xor(L23.y, 16);  S23.y += __shfl_xor(S23.y, 16);
    first += __shfl_xor(first, 16);

    float t = L01.x * L01.x - S01.x + L01.y * L01.y - S01.y
            + L23.x * L23.x - S23.x + L23.y * L23.y - S23.y;
#pragma unroll
    for (int m = 8; m >= 1; m >>= 1) {
        t     += __shfl_xor(t, m);
        first += __shfl_xor(first, m);
    }

    if (lane32 == 0) {
        const float z = first + w0[0] + 0.5f * t;
        out[b] = 1.f / (1.f + __expf(-z));
    }
}

extern "C" void kernel_launch(void* const* d_in, const int* in_sizes, int n_in,
                              void* d_out, int out_size, void* d_ws, size_t ws_size,
                              hipStream_t stream) {
    const float* dense  = (const float*)d_in[0];
    const int*   sparse = (const int*)d_in[1];
    const float* w0     = (const float*)d_in[2];
    const float* w      = (const float*)d_in[3];
    const float* V      = (const float*)d_in[4];
    float* out = (float*)d_out;

    unsigned char* flags = (unsigned char*)d_ws;              // 2.6 MB
    unsigned*      Vt    = (unsigned*)((char*)d_ws + FL_PAD); // 333 MB, 128B records

    hipMemsetAsync(flags, 0, FL_PAD, stream);                 // graph-capturable
    fm_mark<<<N_MARK / 256, 256, 0, stream>>>(sparse, flags);
    fm_prep<<<FL_PAD / 256, 256, 0, stream>>>(V, w, flags, Vt);
    fm_gather<<<(FM_BATCH * 32) / 256, 256, 0, stream>>>(
        dense, sparse, w0, Vt, out);
}

// Round 16
// 102.188 us; speedup vs baseline: 1.1507x; 1.1507x over previous
//
#include <hip/hip_runtime.h>
#include <hip/hip_fp16.h>
#include <stdint.h>

#define FM_BATCH 16384
#define ND 13
#define NF 26
#define FS 100000
#define FL 2600013            // 26*100000 + 13
#define FL_PAD 2600192        // 10157 * 256

// ws layout: flags [FL_PAD] bytes (2.6 MB), then Vt [FL_PAD][16] u32 (166 MB)
#define N_MARK  (FM_BATCH * NF)         // 425984

// ---- Kernel 0: mark referenced features (races write the same value 1) ----
__global__ __launch_bounds__(256) void fm_mark(const int* __restrict__ sparse,
                                               unsigned char* __restrict__ flags)
{
    const int t = blockIdx.x * 256 + threadIdx.x;   // t = b*26 + f, flat over sparse
    const int f = t % NF;
    flags[ND + f * FS + sparse[t]] = 1;
    if (t < ND) flags[t] = 1;                       // dense features always present
}

// ---- Kernel 1: transpose + fp16-quantize referenced columns of V ----
// LDS-staged: each wave reads 8 whole rows of the block's 256-column panel
// as back-to-back dword instructions (1 KB sequential run/row, 32 loads in
// flight/thread). fp32 staged to LDS [col][row] (pad 36), then per-column
// fp16 pack + flag-gated 64 B record store (~27 MB written).
__global__ __launch_bounds__(256) void fm_prep(const float* __restrict__ V,
                                               const unsigned char* __restrict__ flags,
                                               unsigned* __restrict__ Vt)
{
    __shared__ float stage[256][36];   // 36.9 KB; pad 36: col base 144 B (16B-aligned)
    const int j0 = blockIdx.x * 256;
    const int t = threadIdx.x;
    const int w = t >> 6, l = t & 63;

    float va[8][4];
    if (j0 + 256 <= FL) {
#pragma unroll
        for (int p = 0; p < 8; ++p) {               // rows w, w+4, ..., w+28
            const float* rp = V + (size_t)(w + 4 * p) * FL + j0;
#pragma unroll
            for (int i = 0; i < 4; ++i)
                va[p][i] = rp[i * 64 + l];
        }
    } else {
        // tail panel (one block): per-element guard
#pragma unroll
        for (int p = 0; p < 8; ++p) {
#pragma unroll
            for (int i = 0; i < 4; ++i) {
                const int j = j0 + i * 64 + l;
                va[p][i] = (j < FL) ? V[(size_t)(w + 4 * p) * FL + j] : 0.f;
            }
        }
    }

#pragma unroll
    for (int p = 0; p < 8; ++p)
#pragma unroll
        for (int i = 0; i < 4; ++i)
            stage[i * 64 + l][w + 4 * p] = va[p][i];
    __syncthreads();

    const int j = j0 + t;
    if (j < FL && flags[j]) {
        unsigned pk[16];
#pragma unroll
        for (int r = 0; r < 16; ++r)
            pk[r] = (unsigned)__half_as_ushort(__float2half_rn(stage[t][2 * r])) |
                    ((unsigned)__half_as_ushort(__float2half_rn(stage[t][2 * r + 1])) << 16);
        unsigned* dst = Vt + (size_t)j * 16;
#pragma unroll
        for (int c = 0; c < 4; ++c)
            *(uint4*)(dst + 4 * c) = make_uint4(pk[4 * c], pk[4 * c + 1],
                                                pk[4 * c + 2], pk[4 * c + 3]);
    }
}

// ---- Kernel 2: the whole FM. 32 lanes/sample = 16 k-lanes x 2 field-halves.
// 2048 blocks -> 32 waves/CU (max occupancy).
__global__ __launch_bounds__(256) void fm_gather(
    const float* __restrict__ dense,   // [BATCH][13]
    const int*   __restrict__ sparse,  // [BATCH][26]
    const float* __restrict__ w0,      // [1]
    const float* __restrict__ w,       // [FL]
    const unsigned* __restrict__ Vt,   // [FL_PAD][16] u32 (32 fp16)
    float* __restrict__ out)           // [BATCH]
{
    const int tid = blockIdx.x * 256 + threadIdx.x;
    const int b = tid >> 5;            // sample
    const int lane32 = tid & 31;
    const int q = lane32 & 15;         // k-pair slot: ks {2q, 2q+1}
    const int h = lane32 >> 4;         // field half

    float L0 = 0.f, L1 = 0.f, S0 = 0.f, S1 = 0.f, first = 0.f;
    const float* __restrict__ db = dense + b * ND;
    const int*   __restrict__ sb = sparse + b * NF;

    if (h == 0) {
#pragma unroll
        for (int d = 0; d < ND; ++d) {
            const float x = db[d];
            const unsigned r = Vt[(size_t)d * 16 + q];
            const float2 v = __half22float2(*(const __half2*)&r);
            first += x * w[d];
            const float a = x * v.x, c = x * v.y;
            L0 += a; S0 += a * a;
            L1 += c; S1 += c * c;
        }
    }

    const int f0 = h * 13;
#pragma unroll
    for (int ff = 0; ff < 13; ++ff) {
        const int f = f0 + ff;
        const int idx = ND + f * FS + sb[f];
        const unsigned r = Vt[(size_t)idx * 16 + q];
        const float2 v = __half22float2(*(const __half2*)&r);
        first += w[idx];               // same addr across the 16 q-lanes -> broadcast
        L0 += v.x; S0 += v.x * v.x;
        L1 += v.y; S1 += v.y * v.y;
    }

    // combine the two field-halves per k (xor 16 swaps halves)
    L0 += __shfl_xor(L0, 16);  S0 += __shfl_xor(S0, 16);
    L1 += __shfl_xor(L1, 16);  S1 += __shfl_xor(S1, 16);
    first += __shfl_xor(first, 16);

    float t = L0 * L0 - S0 + L1 * L1 - S1;
    t += __shfl_xor(t, 1);
    t += __shfl_xor(t, 2);
    t += __shfl_xor(t, 4);
    t += __shfl_xor(t, 8);             // sum over the 16 q-lanes

    if (lane32 == 0) {
        const float z = first + w0[0] + 0.5f * t;
        out[b] = 1.f / (1.f + __expf(-z));
    }
}

extern "C" void kernel_launch(void* const* d_in, const int* in_sizes, int n_in,
                              void* d_out, int out_size, void* d_ws, size_t ws_size,
                              hipStream_t stream) {
    const float* dense  = (const float*)d_in[0];
    const int*   sparse = (const int*)d_in[1];
    const float* w0     = (const float*)d_in[2];
    const float* w      = (const float*)d_in[3];
    const float* V      = (const float*)d_in[4];
    float* out = (float*)d_out;

    unsigned char* flags = (unsigned char*)d_ws;              // 2.6 MB
    unsigned*      Vt    = (unsigned*)((char*)d_ws + FL_PAD); // 166 MB, 256B-aligned

    hipMemsetAsync(flags, 0, FL_PAD, stream);                 // graph-capturable
    fm_mark<<<N_MARK / 256, 256, 0, stream>>>(sparse, flags);
    fm_prep<<<FL_PAD / 256, 256, 0, stream>>>(V, flags, Vt);
    fm_gather<<<(FM_BATCH * 32) / 256, 256, 0, stream>>>(
        dense, sparse, w0, w, Vt, out);
}